// Round 7
// baseline (257.188 us; speedup 1.0000x reference)
//
#include <hip/hip_runtime.h>
#include <stdint.h>

#define LOG_N 12
#define N 4096
#define NPAIR 2048
#define ROWS 4
#define NT 512
#define TWA_QUADS (12*512)   // reorganized phase-A twiddles: 96 KB in d_ws

// LDS bank-deconflict swizzle: bijection on [0,4096); <=2-way bank aliasing
// for all 4 ownership patterns (contig, stride-8, -64, -512). Only touches
// bits 2..5, keyed on bits >=3 -> aligned 64-blocks map onto themselves, so
// wave-private slices stay wave-private.
__device__ __forceinline__ int swz(int e){
  return e ^ (((e>>6)&7)<<3) ^ (((e>>3)&1)<<2);
}

// ---- Preprocess: transpose phase-A twiddles so thread t's m-th quad of
// stage ls sits at twA[(ls*4+m)*512 + t] (lane-stride 16 B -> coalesced).
__global__ void reorg_twA(const float4* __restrict__ tw, float4* __restrict__ twA){
  const int b = blockIdx.x;      // b = ls*4+m, 12 blocks
  const int t = threadIdx.x;     // 512 threads
  const int ls = b >> 2, m = b & 3;
  twA[b*NT + t] = tw[ls*NPAIR + 4*t + m];
}

// Phase A (stages 0,1,2) from reorganized twiddles: coalesced loads.
__device__ __forceinline__ void phaseA(float (&v)[ROWS][8], int t,
                                       const float4* __restrict__ twA){
#pragma unroll
  for(int sub=0; sub<3; ++sub){
#pragma unroll
    for(int m=0;m<4;++m){
      const int k0 = (sub==0) ? (2*m) : (sub==1) ? (((m>>1)<<2)|(m&1)) : m;
      const int k1 = k0 + (1<<sub);
      const float4 q = twA[(sub*4+m)*NT + t];
#pragma unroll
      for(int r=0;r<ROWS;++r){
        const float x0=v[r][k0], x1=v[r][k1];
        v[r][k0] = fmaf(q.x,x0,q.y*x1);
        v[r][k1] = fmaf(q.z,x0,q.w*x1);
      }
    }
  }
}

// One radix-8 phase = 3 butterfly stages; element k of each row is at
// global position base + (k << LS0). LS0 = 3,6,9 (lane-contiguous twiddle
// access: ~8 cache lines per wave-instr, the f4 minimum).
template<int LS0>
__device__ __forceinline__ void phase3(float (&v)[ROWS][8], int base,
                                       const float4* __restrict__ twq4){
#pragma unroll
  for(int sub=0; sub<3; ++sub){
    const int ls = LS0 + sub;
    const float4* __restrict__ twq = twq4 + ls*NPAIR;
#pragma unroll
    for(int m=0;m<4;++m){
      const int k0 = (sub==0) ? (2*m) : (sub==1) ? (((m>>1)<<2)|(m&1)) : m;
      const int k1 = k0 + (1<<sub);
      const int pos0 = base + (k0<<LS0);
      const int p = ((pos0>>(ls+1))<<ls) | (pos0 & ((1<<ls)-1));
      const float4 q = twq[p];
#pragma unroll
      for(int r=0;r<ROWS;++r){
        const float x0=v[r][k0], x1=v[r][k1];
        v[r][k0] = fmaf(q.x,x0,q.y*x1);
        v[r][k1] = fmaf(q.z,x0,q.w*x1);
      }
    }
  }
}

// ROUND-6 CHANGE (re-run; r6 bench died with "no ROCm-capable device" before
// any kernel ran — hypothesis untested): all intra-wave fences/sched_barriers
// REMOVED. Rationale: r0==r3 (barriers vs fences: null) and r5 (coalescing
// phase A, which has no wall above it, helped; B/C/D, already coalesced but
// wall-trapped, didn't) point at the sched_barrier(0) walls serializing
// [drain -> 12 L2 twiddle loads -> FMA] per phase with zero overlap.
// Correctness without fences: A->B and B->C exchanges are same-wave (8- and
// 64-thread groups; swz keeps 64-blocks intact), and a wave's DS instructions
// execute in order (r4's B->C already relied on same-wave WAR ordering and
// passed). The compiler can't disprove LDS aliasing -> preserves DS program
// order; it auto-inserts lgkmcnt before ds_read uses. Only C->D is
// cross-wave -> keeps syncthreads.
__global__ __launch_bounds__(NT, 4)   // measured: cap 64 VGPR, no spill (r3/r5)
void butterfly_k(const float* __restrict__ x, const float* __restrict__ tw,
                 const float4* __restrict__ twA, float* __restrict__ out)
{
  __shared__ float lds[2*N];            // 32 KB, pair-pumped exchanges
  const int t = threadIdx.x;
  const size_t row0 = (size_t)blockIdx.x * ROWS;
  const float4* twq4 = (const float4*)tw;

  float v[ROWS][8];

  // ---- global load, phase-A ownership: e = 8t + k (2 x dwordx4 per row)
  {
    const float4* px = (const float4*)x;
#pragma unroll
    for(int r=0;r<ROWS;++r){
      const float4 a = px[(row0+r)*(N/4) + 2*t];
      const float4 b = px[(row0+r)*(N/4) + 2*t + 1];
      v[r][0]=a.x; v[r][1]=a.y; v[r][2]=a.z; v[r][3]=a.w;
      v[r][4]=b.x; v[r][5]=b.y; v[r][6]=b.z; v[r][7]=b.w;
    }
  }

  phaseA(v, t, twA);                    // stages 0,1,2 — coalesced twiddles

  const int baseB = ((t>>3)<<6) | (t&7);
  // ---- exchange A -> B: same-wave (8-thread groups). Pair-pumped through
  // the 2-row buffer; in-order DS queue provides W->R (RAW, same region) and
  // R(p0)->W(p1) (WAR, same addresses) ordering. No fences.
  {
    const int Bb = (8*t) ^ (((t>>3)&7)<<3);
    const int flip = (t&1)<<2;
#pragma unroll
    for(int pp=0;pp<2;++pp){
#pragma unroll
      for(int rr=0;rr<2;++rr){
        float* L = lds + rr*N;
        const int r = 2*pp + rr;
        *(float4*)(L + Bb + flip)     = make_float4(v[r][0],v[r][1],v[r][2],v[r][3]);
        *(float4*)(L + Bb + (4^flip)) = make_float4(v[r][4],v[r][5],v[r][6],v[r][7]);
      }
#pragma unroll
      for(int k=0;k<8;++k){
        const int a = swz(baseB + (k<<3));
#pragma unroll
        for(int rr=0;rr<2;++rr) v[2*pp+rr][k] = lds[rr*N + a];
      }
    }
  }

  phase3<3>(v, baseB, twq4);            // stages 3,4,5 (strides 8,16,32)

  const int baseC = ((t>>6)<<9) | (t&63);
  // ---- exchange B -> C: same-wave (64-thread groups = one wave). No fences.
#pragma unroll
  for(int pp=0;pp<2;++pp){
#pragma unroll
    for(int k=0;k<8;++k){
      const int a = swz(baseB + (k<<3));
#pragma unroll
      for(int rr=0;rr<2;++rr) lds[rr*N + a] = v[2*pp+rr][k];
    }
#pragma unroll
    for(int k=0;k<8;++k){
      const int a = swz(baseC + (k<<6));
#pragma unroll
      for(int rr=0;rr<2;++rr) v[2*pp+rr][k] = lds[rr*N + a];
    }
  }

  phase3<6>(v, baseC, twq4);            // stages 6,7,8 (strides 64,128,256)

  // ---- exchange C -> D: crosses waves -> syncthreads (the only real
  // barriers in the kernel). Rows {0,1} then {2,3} through the 32 KB buffer.
#pragma unroll
  for(int k=0;k<8;++k){
    const int a = swz(baseC + (k<<6));
#pragma unroll
    for(int rr=0;rr<2;++rr) lds[rr*N + a] = v[rr][k];
  }
  __syncthreads();
#pragma unroll
  for(int k=0;k<8;++k){
    const int a = swz(t + (k<<9));
#pragma unroll
    for(int rr=0;rr<2;++rr) v[rr][k] = lds[rr*N + a];
  }
  __syncthreads();                      // all pair-0 reads done before clobber
#pragma unroll
  for(int k=0;k<8;++k){
    const int a = swz(baseC + (k<<6));
#pragma unroll
    for(int rr=0;rr<2;++rr) lds[rr*N + a] = v[2+rr][k];
  }
  __syncthreads();
#pragma unroll
  for(int k=0;k<8;++k){
    const int a = swz(t + (k<<9));
#pragma unroll
    for(int rr=0;rr<2;++rr) v[2+rr][k] = lds[rr*N + a];
  }

  phase3<9>(v, t, twq4);                // stages 9,10,11 (strides 512,1024,2048)

  // ---- store: element t + 512k of each row; lanes consecutive -> coalesced
#pragma unroll
  for(int r=0;r<ROWS;++r){
    float* po = out + (row0+r)*N + t;
#pragma unroll
    for(int k=0;k<8;++k) po[(size_t)(k<<9)] = v[r][k];
  }
}

extern "C" void kernel_launch(void* const* d_in, const int* in_sizes, int n_in,
                              void* d_out, int out_size, void* d_ws, size_t ws_size,
                              hipStream_t stream) {
  const float* x  = (const float*)d_in[0];   // (8192, 4096) fp32
  const float* tw = (const float*)d_in[1];   // (1,1,12,2048,2,2) fp32
  float* out = (float*)d_out;                // (8192, 4096) fp32
  const int batch = in_sizes[0] / N;         // 8192
  dim3 grid(batch / ROWS), block(NT);

  hipLaunchKernelGGL(reorg_twA, dim3(12), dim3(NT), 0, stream,
                     (const float4*)tw, (float4*)d_ws);
  hipLaunchKernelGGL(butterfly_k, grid, block, 0, stream,
                     x, tw, (const float4*)d_ws, out);
}